// Round 7
// baseline (3222.365 us; speedup 1.0000x reference)
//
#include <hip/hip_runtime.h>
#include <cstdint>
#include <cstddef>
#include <math.h>

constexpr int N = 4096;
constexpr int D = 256;
constexpr int N1 = N + 1;           // 4097
constexpr int MAXNZ = 256;          // max ROI neighbors per row (E[129], max~180)
constexpr int MAXIT = 100;
constexpr int NBS = 257;            // sinkhorn blocks: 257 blocks x 16 waves >= 4097 rows
constexpr double SNAP_THETA = 3e-6; // ~1.5 f32 ulp at |val|~17: near-tie class width

// output layout (float32 buffer, concatenated in reference return order)
constexpr size_t OFF_SOFT = 0;
constexpr size_t OFF_MS0  = (size_t)N1 * N1;            // 16785409
constexpr size_t OFF_MS1  = OFF_MS0 + N;
constexpr size_t OFF_IDX0 = OFF_MS1 + N;
constexpr size_t OFF_IDX1 = OFF_IDX0 + 2 * (size_t)N;

struct Ws {
  double vals_r[(size_t)N * MAXNZ];
  double vals_c[(size_t)N * MAXNZ];
  int    cols_r[(size_t)N * MAXNZ];
  int    rows_c[(size_t)N * MAXNZ];
  double inv1[N], inv2[N];
  int    cnt_r[N], cnt_c[N];
  double u[N1], v[N1], expu[N1], expv[N1];
  double SuArr[MAXIT], SvArr[MAXIT + 1];
  double partA[NBS];
  int    cntU[MAXIT], cntV[MAXIT];
  int    nnzTotal;
  unsigned long long medPrefix;
  int    medK;
  double binScore, bcz;
  int    hist[8 * 256];
  double vals0[N * 2], vals1[N * 2];
  int    idx0[N * 2], idx1[N * 2];
  int    valid0[2 * N];
};

__device__ __forceinline__ double wsum64d(double x) {
  #pragma unroll
  for (int m = 1; m < 64; m <<= 1) x += __shfl_xor(x, m, 64);
  return x;
}
__device__ __forceinline__ void ag_store(double* p, double x) {
  __hip_atomic_store(p, x, __ATOMIC_RELAXED, __HIP_MEMORY_SCOPE_AGENT);
}
__device__ __forceinline__ double ag_load(double* p) {
  return __hip_atomic_load(p, __ATOMIC_RELAXED, __HIP_MEMORY_SCOPE_AGENT);
}

// ---------------- init ----------------
__global__ void k_init(Ws* ws) {
  int tid = threadIdx.x;
  for (int i = tid; i < N1; i += 256) {
    ws->u[i] = 0.0; ws->v[i] = 0.0; ws->expu[i] = 1.0; ws->expv[i] = 1.0;
  }
  for (int i = tid; i < MAXIT; i += 256) { ws->cntU[i] = 0; ws->cntV[i] = 0; }
  for (int i = tid; i < 8 * 256; i += 256) ws->hist[i] = 0;
  if (tid == 0) {
    ws->nnzTotal = 0; ws->medPrefix = 0ull; ws->medK = 0;
    ws->SvArr[0] = 4096.0;      // sum exp(v=0) over 4096 cols
  }
}

// ---------------- inverse norms (f64) ----------------
__global__ void k_norms(const float* e1, const float* e2, Ws* ws) {
  int tid = threadIdx.x, lane = tid & 63, wid = tid >> 6;
  int r = blockIdx.x * 4 + wid;
  if (r >= 2 * N) return;
  const float* p = (r < N) ? (e1 + (size_t)r * D) : (e2 + (size_t)(r - N) * D);
  double s = 0.0;
  #pragma unroll
  for (int k = lane; k < D; k += 64) { double x = (double)p[k]; s += x * x; }
  s = wsum64d(s);
  if (lane == 0) {
    double invn = 1.0 / fmax(sqrt(s), 1e-12);
    if (r < N) ws->inv1[r] = invn; else ws->inv2[r - N] = invn;
  }
}

// ---------------- CSR / CSC build (f32 mask; f64 values) ----------------
template <bool CSC>
__global__ void k_build(const float* e1, const float* e2,
                        const float* l1, const float* l2, Ws* ws) {
  __shared__ float erow[D];
  __shared__ int hcols[256];
  __shared__ int wcnt[4];
  __shared__ int s_hcnt;
  int self = blockIdx.x;
  int tid = threadIdx.x, lane = tid & 63, wid = tid >> 6;
  const float* eself = CSC ? (e2 + (size_t)self * D) : (e1 + (size_t)self * D);
  erow[tid] = eself[tid];
  float sx = CSC ? l2[self * 2] : l1[self * 2];
  float sy = CSC ? l2[self * 2 + 1] : l1[self * 2 + 1];
  double invs = CSC ? ws->inv2[self] : ws->inv1[self];
  const float* eoth = CSC ? e1 : e2;
  const float* loth = CSC ? l1 : l2;
  const double* invoth = CSC ? ws->inv1 : ws->inv2;
  double* valsOut = CSC ? ws->vals_c : ws->vals_r;
  int* colsOut = CSC ? ws->rows_c : ws->cols_r;
  size_t base = (size_t)self * MAXNZ;
  int written = 0;
  __syncthreads();
  for (int c0 = 0; c0 < N; c0 += 256) {
    int j = c0 + tid;
    float dx = sx - loth[j * 2];
    float dy = sy - loth[j * 2 + 1];
    float dist = sqrtf(dx * dx + dy * dy);
    bool in = dist < 0.1f;
    unsigned long long m = __ballot(in);
    int rank = __popcll(m & ((1ull << lane) - 1ull));
    if (lane == 0) wcnt[wid] = (int)__popcll(m);
    __syncthreads();
    int wb = 0;
    for (int w = 0; w < wid; ++w) wb += wcnt[w];
    if (in) hcols[wb + rank] = j;
    if (tid == 0) s_hcnt = wcnt[0] + wcnt[1] + wcnt[2] + wcnt[3];
    __syncthreads();
    int hc = s_hcnt;
    for (int h = wid; h < hc; h += 4) {      // one wave per hit
      int j2 = hcols[h];
      const float* po = eoth + (size_t)j2 * D;
      double acc = 0.0;
      #pragma unroll
      for (int k = lane; k < D; k += 64) acc += (double)erow[k] * (double)po[k];
      acc = wsum64d(acc);
      if (lane == 0) {
        double i1v = CSC ? invoth[j2] : invs;   // inv1[row]
        double i2v = CSC ? invs : invoth[j2];   // inv2[col]
        double cross = (acc * i1v) * i2v;
        double val = (cross + 1.0) / 1.000001;  // (cross+1)/(2*TAU+1e-06)
        int slot = written + h;
        if (slot < MAXNZ) { valsOut[base + slot] = val; colsOut[base + slot] = j2; }
      }
    }
    written += hc;
    __syncthreads();
  }
  if (tid == 0) {
    int cnt = min(written, MAXNZ);
    if (CSC) ws->cnt_c[self] = cnt;
    else { ws->cnt_r[self] = cnt; atomicAdd(&ws->nnzTotal, cnt); }
  }
}

// ---------------- nonzero-median via 8-pass radix select on double bits ----------------
__global__ void k_hist(Ws* ws, int round) {
  __shared__ int lh[256];
  lh[threadIdx.x] = 0;
  __syncthreads();
  int shift = 56 - 8 * round;
  unsigned long long prefix = ws->medPrefix;
  unsigned long long hm = (round == 0) ? 0ull : (~0ull << (shift + 8));
  int total = N * MAXNZ;
  for (int s = blockIdx.x * blockDim.x + threadIdx.x; s < total; s += gridDim.x * blockDim.x) {
    int row = s >> 8, e = s & (MAXNZ - 1);
    if (e < ws->cnt_r[row]) {
      unsigned long long bits = __double_as_longlong(ws->vals_r[(size_t)row * MAXNZ + e]);
      if ((bits & hm) == (prefix & hm)) atomicAdd(&lh[(int)((bits >> shift) & 255)], 1);
    }
  }
  __syncthreads();
  if (lh[threadIdx.x]) atomicAdd(&ws->hist[round * 256 + threadIdx.x], lh[threadIdx.x]);
}

__global__ void k_select(Ws* ws, int round) {
  __shared__ int cum[256];
  int tid = threadIdx.x;
  if (round == 0 && tid == 0) ws->medK = (ws->nnzTotal - 1) >> 1;
  __syncthreads();
  int k = ws->medK;
  int h = ws->hist[round * 256 + tid];
  cum[tid] = h;
  __syncthreads();
  for (int off = 1; off < 256; off <<= 1) {
    int val = (tid >= off) ? cum[tid - off] : 0;
    __syncthreads();
    cum[tid] += val;
    __syncthreads();
  }
  int below = cum[tid] - h;
  if (cum[tid] > k && below <= k) {   // unique thread
    int shift = 56 - 8 * round;
    unsigned long long p = ws->medPrefix | ((unsigned long long)tid << shift);
    ws->medPrefix = p;
    ws->medK = k - below;
    if (round == 7) {
      double bs = __longlong_as_double(p);
      ws->binScore = bs;
      ws->bcz = bs / 1.000001;
    }
  }
}

// ---------------- sinkhorn passes (sparse, f64, fixed count) ----------------
__global__ void k_upass(Ws* ws, const int* d_iters, int t) {
  if (t >= d_iters[0]) return;
  int tid = threadIdx.x, lane = tid & 63, wid = tid >> 6;
  double Sv = ws->SvArr[t];
  double v4096 = ws->v[N];
  double bcz = ws->bcz;
  double norm0 = -log(8192.0);
  int row = blockIdx.x * 16 + wid;
  __shared__ double seu[16];
  double eu = 0.0;
  if (row <= N) {
    double unew;
    if (row < N) {
      int cnt = ws->cnt_r[row];
      size_t base = (size_t)row * MAXNZ;
      double acc = 0.0;
      for (int e = lane; e < cnt; e += 64) {
        double zc = ws->vals_r[base + e] / 1.000001;
        int c = ws->cols_r[base + e];
        acc += expm1(zc) * ws->expv[c];
      }
      acc = wsum64d(acc);
      double total = Sv + acc + exp(bcz + v4096);
      unew = norm0 - log(total);
    } else {
      unew = (log(4096.0) + norm0) - bcz - log(Sv + exp(v4096));
    }
    if (lane == 0) {
      ws->u[row] = unew;
      if (row < N) { eu = exp(unew); ws->expu[row] = eu; }
    }
  }
  if (lane == 0) seu[wid] = eu;
  __syncthreads();
  if (tid == 0) {
    double pe = 0.0;
    #pragma unroll
    for (int w = 0; w < 16; ++w) pe += seu[w];
    ag_store(&ws->partA[blockIdx.x], pe);
  }
  __shared__ int isLast;
  if (tid == 0) {
    __threadfence();
    int old = __hip_atomic_fetch_add(&ws->cntU[t], 1, __ATOMIC_ACQ_REL, __HIP_MEMORY_SCOPE_AGENT);
    isLast = (old == (int)gridDim.x - 1) ? 1 : 0;
  }
  __syncthreads();
  if (!isLast) return;
  __shared__ double r1[1024];
  double a = 0.0;
  for (int i = tid; i < NBS; i += 1024) a += ag_load(&ws->partA[i]);
  r1[tid] = a;
  __syncthreads();
  for (int off = 512; off > 0; off >>= 1) {
    if (tid < off) r1[tid] += r1[tid + off];
    __syncthreads();
  }
  if (tid == 0) ws->SuArr[t] = r1[0];
}

__global__ void k_vpass(Ws* ws, const int* d_iters, int t) {
  if (t >= d_iters[0]) return;
  int tid = threadIdx.x, lane = tid & 63, wid = tid >> 6;
  double Su = ws->SuArr[t];
  double u4096 = ws->u[N];
  double bcz = ws->bcz;
  double norm0 = -log(8192.0);
  int col = blockIdx.x * 16 + wid;
  __shared__ double sev[16];
  double ev = 0.0;
  if (col <= N) {
    double vnew;
    if (col < N) {
      int cnt = ws->cnt_c[col];
      size_t base = (size_t)col * MAXNZ;
      double acc = 0.0;
      for (int e = lane; e < cnt; e += 64) {
        double zc = ws->vals_c[base + e] / 1.000001;
        int r = ws->rows_c[base + e];
        acc += expm1(zc) * ws->expu[r];
      }
      acc = wsum64d(acc);
      double total = Su + acc + exp(bcz + u4096);
      vnew = norm0 - log(total);
    } else {
      vnew = (log(4096.0) + norm0) - bcz - log(Su + exp(u4096));
    }
    if (lane == 0) {
      ws->v[col] = vnew;
      if (col < N) { ev = exp(vnew); ws->expv[col] = ev; }
    }
  }
  if (lane == 0) sev[wid] = ev;
  __syncthreads();
  if (tid == 0) {
    double pv = 0.0;
    #pragma unroll
    for (int w = 0; w < 16; ++w) pv += sev[w];
    ag_store(&ws->partA[blockIdx.x], pv);
  }
  __shared__ int isLast;
  if (tid == 0) {
    __threadfence();
    int old = __hip_atomic_fetch_add(&ws->cntV[t], 1, __ATOMIC_ACQ_REL, __HIP_MEMORY_SCOPE_AGENT);
    isLast = (old == (int)gridDim.x - 1) ? 1 : 0;
  }
  __syncthreads();
  if (!isLast) return;
  __shared__ double r1[1024];
  double a = 0.0;
  for (int i = tid; i < NBS; i += 1024) a += ag_load(&ws->partA[i]);
  r1[tid] = a;
  __syncthreads();
  for (int off = 512; off > 0; off >>= 1) {
    if (tid < off) r1[tid] += r1[tid + off];
    __syncthreads();
  }
  if (tid == 0) ws->SvArr[t + 1] = r1[0];
}

// ---------------- dense soft output (f64 values, f32 store) ----------------
__global__ void k_soft(Ws* ws, float* out) {
  __shared__ double srow[N];
  int i = blockIdx.x, tid = threadIdx.x;
  double norm0 = -log(8192.0);
  double bs = ws->binScore;
  if (i < N) {
    for (int j = tid; j < N; j += 256) srow[j] = 0.0;
    __syncthreads();
    int cnt = ws->cnt_r[i];
    size_t base = (size_t)i * MAXNZ;
    for (int e = tid; e < cnt; e += 256) srow[ws->cols_r[base + e]] = ws->vals_r[base + e];
    __syncthreads();
    double ui = ws->u[i];
    size_t ob = (size_t)i * N1;
    for (int j = tid; j < N; j += 256) out[ob + j] = (float)(((srow[j] + ui) + ws->v[j]) - norm0);
    if (tid == 0) out[ob + N] = (float)(((bs + ui) + ws->v[N]) - norm0);
  } else {
    double un = ws->u[N];
    size_t ob = (size_t)N * N1;
    for (int j = tid; j < N; j += 256) out[ob + j] = (float)(((bs + un) + ws->v[j]) - norm0);
    if (tid == 0) out[ob + N] = (float)(((bs + un) + ws->v[N]) - norm0);
  }
}

// ---------------- top-3 with indices; near-tie classes resolved by ascending index ----------------
struct T3 { double v1, v2, v3; int i1, i2, i3; };
__device__ __forceinline__ bool betterD(double a, int ia, double b, int ib) {
  return a > b || (a == b && ia < ib);
}
__device__ __forceinline__ void insT3(T3& t, double nv, int ni) {
  if (betterD(nv, ni, t.v1, t.i1)) { t.v3 = t.v2; t.i3 = t.i2; t.v2 = t.v1; t.i2 = t.i1; t.v1 = nv; t.i1 = ni; }
  else if (betterD(nv, ni, t.v2, t.i2)) { t.v3 = t.v2; t.i3 = t.i2; t.v2 = nv; t.i2 = ni; }
  else if (betterD(nv, ni, t.v3, t.i3)) { t.v3 = nv; t.i3 = ni; }
}

template <bool COL>
__global__ void k_top2(Ws* ws) {
  __shared__ double sval[N];
  __shared__ T3 red[256];
  int i = blockIdx.x, tid = threadIdx.x;
  double norm0 = -log(8192.0);
  for (int j = tid; j < N; j += 256) sval[j] = 0.0;
  __syncthreads();
  int cnt = COL ? ws->cnt_c[i] : ws->cnt_r[i];
  size_t base = (size_t)i * MAXNZ;
  const int* idxs = COL ? ws->rows_c : ws->cols_r;
  const double* vls = COL ? ws->vals_c : ws->vals_r;
  for (int e = tid; e < cnt; e += 256) sval[idxs[base + e]] = vls[base + e];
  __syncthreads();
  double fixedUV = COL ? ws->v[i] : ws->u[i];
  T3 t; t.v1 = -INFINITY; t.v2 = -INFINITY; t.v3 = -INFINITY;
  t.i1 = 0x7fffffff; t.i2 = 0x7fffffff; t.i3 = 0x7fffffff;
  for (int j = tid; j < N; j += 256) {
    double val = COL ? (((sval[j] + ws->u[j]) + fixedUV) - norm0)
                     : (((sval[j] + fixedUV) + ws->v[j]) - norm0);
    insT3(t, val, j);
  }
  red[tid] = t;
  __syncthreads();
  for (int off = 128; off > 0; off >>= 1) {
    if (tid < off) {
      T3 a = red[tid];
      T3 b = red[tid + off];
      insT3(a, b.v1, b.i1);
      insT3(a, b.v2, b.i2);
      insT3(a, b.v3, b.i3);
      red[tid] = a;
    }
    __syncthreads();
  }
  if (tid == 0) {
    T3 a = red[0];
    // near-tie snap: emulate reference f32 exact-tie resolution (stable -> lower index first).
    // bubble passes so a 3-element tie class sorts fully by index.
    if (a.v2 - a.v3 < SNAP_THETA && a.i3 < a.i2) { double tv = a.v2; int ti = a.i2; a.v2 = a.v3; a.i2 = a.i3; a.v3 = tv; a.i3 = ti; }
    if (a.v1 - a.v2 < SNAP_THETA && a.i2 < a.i1) { double tv = a.v1; int ti = a.i1; a.v1 = a.v2; a.i1 = a.i2; a.v2 = tv; a.i2 = ti; }
    if (a.v2 - a.v3 < SNAP_THETA && a.i3 < a.i2) { double tv = a.v2; int ti = a.i2; a.v2 = a.v3; a.i2 = a.i3; a.v3 = tv; a.i3 = ti; }
    if (COL) {
      ws->vals1[i * 2] = a.v1; ws->idx1[i * 2] = a.i1;
      ws->vals1[i * 2 + 1] = a.v2; ws->idx1[i * 2 + 1] = a.i2;
    } else {
      ws->vals0[i * 2] = a.v1; ws->idx0[i * 2] = a.i1;
      ws->vals0[i * 2 + 1] = a.v2; ws->idx0[i * 2 + 1] = a.i2;
    }
  }
}

// ---------------- mutual matching ----------------
__global__ void k_match0(Ws* ws, float* out) {
  int r = blockIdx.x * blockDim.x + threadIdx.x;
  if (r >= N) return;
  double msum = 0.0;
  #pragma unroll
  for (int k = 0; k < 2; ++k) {
    int c = ws->idx0[r * 2 + k];
    bool mutual = (ws->idx1[c * 2 + k] == r);
    double ms = mutual ? exp(ws->vals0[r * 2 + k]) : 0.0;
    msum += ms;
    bool valid = mutual && (ms > 0.0);
    ws->valid0[k * N + r] = valid ? 1 : 0;
    out[OFF_IDX0 + (size_t)k * N + r] = valid ? (float)c : -1.0f;
  }
  out[OFF_MS0 + r] = (float)msum;
}

__global__ void k_match1(Ws* ws, float* out) {
  int c = blockIdx.x * blockDim.x + threadIdx.x;
  if (c >= N) return;
  double msum = 0.0;
  #pragma unroll
  for (int k = 0; k < 2; ++k) {
    int r = ws->idx1[c * 2 + k];
    bool mutual = (ws->idx0[r * 2 + k] == c);
    double ms = mutual ? exp(ws->vals1[c * 2 + k]) : 0.0;
    msum += ms;
    bool valid = mutual && (ws->valid0[k * N + r] != 0);
    out[OFF_IDX1 + (size_t)k * N + c] = valid ? (float)r : -1.0f;
  }
  out[OFF_MS1 + c] = (float)msum;
}

extern "C" void kernel_launch(void* const* d_in, const int* in_sizes, int n_in,
                              void* d_out, int out_size, void* d_ws, size_t ws_size,
                              hipStream_t stream) {
  const float* e1 = (const float*)d_in[0];
  const float* e2 = (const float*)d_in[1];
  const float* l1 = (const float*)d_in[2];
  const float* l2 = (const float*)d_in[3];
  const int* iters = (const int*)d_in[4];
  float* out = (float*)d_out;
  Ws* ws = (Ws*)d_ws;

  k_init<<<1, 256, 0, stream>>>(ws);
  k_norms<<<2048, 256, 0, stream>>>(e1, e2, ws);
  k_build<false><<<N, 256, 0, stream>>>(e1, e2, l1, l2, ws);
  k_build<true><<<N, 256, 0, stream>>>(e1, e2, l1, l2, ws);
  for (int r = 0; r < 8; ++r) {
    k_hist<<<1024, 256, 0, stream>>>(ws, r);
    k_select<<<1, 256, 0, stream>>>(ws, r);
  }
  for (int t = 0; t < MAXIT; ++t) {
    k_upass<<<NBS, 1024, 0, stream>>>(ws, iters, t);
    k_vpass<<<NBS, 1024, 0, stream>>>(ws, iters, t);
  }
  k_soft<<<N1, 256, 0, stream>>>(ws, out);
  k_top2<false><<<N, 256, 0, stream>>>(ws);
  k_top2<true><<<N, 256, 0, stream>>>(ws);
  k_match0<<<16, 256, 0, stream>>>(ws, out);
  k_match1<<<16, 256, 0, stream>>>(ws, out);
}